// Round 1
// baseline (774.625 us; speedup 1.0000x reference)
//
#include <hip/hip_runtime.h>

#define B_  64
#define S_  2048
#define H_  512
#define V_  50257
#define NB_ 32
#define L_  64
#define H3_ 1536

typedef float  f32x4  __attribute__((ext_vector_type(4)));
typedef __bf16 bf16x8 __attribute__((ext_vector_type(8)));

struct alignas(16) U4 { unsigned int x, y, z, w; };

__device__ __forceinline__ unsigned int f2bf_bits(float f) {
  unsigned int u = __float_as_uint(f);
  return (u + 0x7fffu + ((u >> 16) & 1u)) >> 16;  // RNE
}

__device__ __forceinline__ float wave_sum(float v) {
#pragma unroll
  for (int off = 32; off > 0; off >>= 1) v += __shfl_xor(v, off, 64);
  return v;
}

// q[b,h] = sum_g hidden[1][b,g] * attn_W[g,h]
__global__ __launch_bounds__(256) void k_q(const float* __restrict__ hidden,
                                           const float* __restrict__ attn_W,
                                           float* __restrict__ q) {
  __shared__ float sh[8 * H_];
  int tid = threadIdx.x;
  int h  = blockIdx.x * 256 + tid;
  int b0 = blockIdx.y * 8;
  const float* h1 = hidden + B_ * H_;
  for (int i = tid; i < 8 * H_; i += 256) sh[i] = h1[b0 * H_ + i];
  __syncthreads();
  float acc[8] = {0.f, 0.f, 0.f, 0.f, 0.f, 0.f, 0.f, 0.f};
  for (int g = 0; g < H_; ++g) {
    float w = attn_W[(size_t)g * H_ + h];
#pragma unroll
    for (int bb = 0; bb < 8; ++bb) acc[bb] += sh[bb * H_ + g] * w;
  }
#pragma unroll
  for (int bb = 0; bb < 8; ++bb) q[(b0 + bb) * H_ + h] = acc[bb];
}

// One wave per (b,n): online-softmax over L=64 rows; eo read exactly once.
__global__ __launch_bounds__(256) void k_attn(
    const float* __restrict__ eo, const float* __restrict__ hidden,
    const float* __restrict__ attn_b, const float* __restrict__ q,
    float* __restrict__ bc, float* __restrict__ attnw_out) {
  int lane = threadIdx.x & 63;
  int idx  = blockIdx.x * 4 + (threadIdx.x >> 6);
  int b = idx >> 5, n = idx & 31;

  const float4* qv = (const float4*)(q + (size_t)b * H_);
  float4 q0 = qv[lane], q1 = qv[64 + lane];

  // c0 = dot(hidden[1][b], attn_b)
  const float4* hv = (const float4*)(hidden + (size_t)B_ * H_ + (size_t)b * H_);
  const float4* av = (const float4*)attn_b;
  float4 hx = hv[lane], hy = hv[64 + lane];
  float4 ax = av[lane], ay = av[64 + lane];
  float c0 = hx.x*ax.x + hx.y*ax.y + hx.z*ax.z + hx.w*ax.w
           + hy.x*ay.x + hy.y*ay.y + hy.z*ay.z + hy.w*ay.w;
  c0 = wave_sum(c0);

  const float4* ev = (const float4*)(eo + (size_t)(b * NB_ + n) * L_ * H_);
  float m = -1e30f, s = 0.f, myscore = 0.f;
  float4 A0 = {0,0,0,0}, A1 = {0,0,0,0};
  for (int l = 0; l < L_; ++l) {
    float4 e0 = ev[l * 128 + lane];
    float4 e1 = ev[l * 128 + 64 + lane];
    float p = e0.x*q0.x + e0.y*q0.y + e0.z*q0.z + e0.w*q0.w
            + e1.x*q1.x + e1.y*q1.y + e1.z*q1.z + e1.w*q1.w;
    p = wave_sum(p) + c0;
    if (lane == l) myscore = p;
    float mnew  = fmaxf(m, p);
    float alpha = __expf(m - mnew);
    float w     = __expf(p - mnew);
    s = s * alpha + w;
    A0.x = A0.x*alpha + w*e0.x; A0.y = A0.y*alpha + w*e0.y;
    A0.z = A0.z*alpha + w*e0.z; A0.w = A0.w*alpha + w*e0.w;
    A1.x = A1.x*alpha + w*e1.x; A1.y = A1.y*alpha + w*e1.y;
    A1.z = A1.z*alpha + w*e1.z; A1.w = A1.w*alpha + w*e1.w;
    m = mnew;
  }
  float inv = 1.f / s;
  float4* bv = (float4*)(bc + (size_t)(b * NB_ + n) * H_);
  float4 o0 = {A0.x*inv, A0.y*inv, A0.z*inv, A0.w*inv};
  float4 o1 = {A1.x*inv, A1.y*inv, A1.z*inv, A1.w*inv};
  bv[lane] = o0; bv[64 + lane] = o1;
  attnw_out[(size_t)(b * NB_ + n) * L_ + lane] = __expf(myscore - m) * inv;
}

// context reduce over n, embedding gather, bf16 conversions of x_cat / h0 / h1
__global__ __launch_bounds__(512) void k_prep(
    const int* __restrict__ ids, const float* __restrict__ hidden,
    const float* __restrict__ baw, const float* __restrict__ emb,
    const float* __restrict__ bc, float* __restrict__ ctx,
    unsigned short* __restrict__ xcatb, unsigned short* __restrict__ h0b,
    unsigned short* __restrict__ h1b, float* __restrict__ out_ctx) {
  int b = blockIdx.x, h = threadIdx.x;
  int id = ids[b];
  float ev = emb[(size_t)id * H_ + h];
  float acc = 0.f;
  for (int n = 0; n < NB_; ++n)
    acc += baw[b * NB_ + n] * bc[(size_t)(b * NB_ + n) * H_ + h];
  ctx[b * H_ + h]      = acc;
  out_ctx[b * H_ + h]  = acc;
  xcatb[b * 1024 + h]        = (unsigned short)f2bf_bits(ev);
  xcatb[b * 1024 + 512 + h]  = (unsigned short)f2bf_bits(acc);
  h0b[b * H_ + h] = (unsigned short)f2bf_bits(hidden[b * H_ + h]);
  h1b[b * H_ + h] = (unsigned short)f2bf_bits(hidden[B_ * H_ + b * H_ + h]);
}

// C[64,N] = A_bf16[64,K] . W_f32[N,K]^T + bias ; MFMA 16x16x32 bf16.
// Block = 4 waves (b-split); each wave covers 16 b x (16*JT) j.
template <int JT>
__global__ __launch_bounds__(256) void k_mv64(
    const float* __restrict__ W, const float* __restrict__ bias,
    const unsigned short* __restrict__ A, float* __restrict__ C,
    int N, int K, int ldC) {
  int tid = threadIdx.x;
  int wv = tid >> 6, lane = tid & 63;
  int mrow = lane & 15, qd = lane >> 4;
  int jbase = blockIdx.x * (16 * JT);
  const unsigned short* ap = A + (size_t)(wv * 16 + mrow) * K + qd * 8;
  f32x4 acc[JT];
  size_t wo[JT];
#pragma unroll
  for (int t = 0; t < JT; ++t) {
    acc[t] = (f32x4){0.f, 0.f, 0.f, 0.f};
    int jr = jbase + t * 16 + mrow; if (jr > N - 1) jr = N - 1;
    wo[t] = (size_t)jr * K + qd * 8;
  }
  for (int k0 = 0; k0 < K; k0 += 32) {
    bf16x8 af = __builtin_bit_cast(bf16x8, *(const U4*)(ap + k0));
#pragma unroll
    for (int t = 0; t < JT; ++t) {
      const float* wp = W + wo[t] + k0;
      float4 w0 = *(const float4*)wp;
      float4 w1 = *(const float4*)(wp + 4);
      U4 braw;
      braw.x = f2bf_bits(w0.x) | (f2bf_bits(w0.y) << 16);
      braw.y = f2bf_bits(w0.z) | (f2bf_bits(w0.w) << 16);
      braw.z = f2bf_bits(w1.x) | (f2bf_bits(w1.y) << 16);
      braw.w = f2bf_bits(w1.z) | (f2bf_bits(w1.w) << 16);
      bf16x8 bf = __builtin_bit_cast(bf16x8, braw);
      acc[t] = __builtin_amdgcn_mfma_f32_16x16x32_bf16(af, bf, acc[t], 0, 0, 0);
    }
  }
#pragma unroll
  for (int t = 0; t < JT; ++t) {
    int j = jbase + t * 16 + mrow;
    if (j < N) {
      float bv = bias[j];
#pragma unroll
      for (int r = 0; r < 4; ++r) {
        int brow = wv * 16 + qd * 4 + r;           // C/D: row = quad*4+reg
        C[(size_t)brow * ldC + j] = acc[t][r] + bv;
      }
    }
  }
}

// GRU gate combine. Optionally builds out_in bf16 = [h_new | context].
__global__ __launch_bounds__(512) void k_gru(
    const float* __restrict__ gx, const float* __restrict__ gh,
    const float* __restrict__ hprev, float* __restrict__ hnew_out,
    unsigned short* __restrict__ hnew_bf, const float* __restrict__ ctx,
    unsigned short* __restrict__ outin) {
  int b = blockIdx.x, i = threadIdx.x;
  size_t g0 = (size_t)b * H3_ + i;
  float xr = gx[g0], xz = gx[g0 + 512], xn = gx[g0 + 1024];
  float hr = gh[g0], hz = gh[g0 + 512], hn = gh[g0 + 1024];
  float r  = 1.f / (1.f + __expf(-(xr + hr)));
  float z  = 1.f / (1.f + __expf(-(xz + hz)));
  float nn = tanhf(xn + r * hn);
  float hp = hprev[b * H_ + i];
  float h  = (1.f - z) * nn + z * hp;
  hnew_out[b * H_ + i] = h;
  hnew_bf[b * H_ + i]  = (unsigned short)f2bf_bits(h);
  if (outin) {
    outin[b * 1024 + i]       = (unsigned short)f2bf_bits(h);
    outin[b * 1024 + 512 + i] = (unsigned short)f2bf_bits(ctx[b * H_ + i]);
  }
}

__global__ __launch_bounds__(1024) void k_lsm(const float* __restrict__ logits,
                                              float* __restrict__ out) {
  int b = blockIdx.x, tid = threadIdx.x;
  int lane = tid & 63, wid = tid >> 6;
  const float* row = logits + (size_t)b * V_;
  __shared__ float red[16];
  float mx = -1e30f;
  for (int j = tid; j < V_; j += 1024) mx = fmaxf(mx, row[j]);
#pragma unroll
  for (int off = 32; off > 0; off >>= 1) mx = fmaxf(mx, __shfl_xor(mx, off, 64));
  if (lane == 0) red[wid] = mx;
  __syncthreads();
  if (tid == 0) {
    float v = red[0];
    for (int i = 1; i < 16; ++i) v = fmaxf(v, red[i]);
    red[0] = v;
  }
  __syncthreads();
  mx = red[0];
  __syncthreads();
  float s = 0.f;
  for (int j = tid; j < V_; j += 1024) s += __expf(row[j] - mx);
  s = wave_sum(s);
  if (lane == 0) red[wid] = s;
  __syncthreads();
  if (tid == 0) {
    float v = 0.f;
    for (int i = 0; i < 16; ++i) v += red[i];
    red[0] = logf(v);
  }
  __syncthreads();
  float lse = mx + red[0];
  for (int j = tid; j < V_; j += 1024) out[(size_t)b * V_ + j] = row[j] - lse;
}

extern "C" void kernel_launch(void* const* d_in, const int* in_sizes, int n_in,
                              void* d_out, int out_size, void* d_ws, size_t ws_size,
                              hipStream_t stream) {
  const int*   ids    = (const int*)d_in[0];
  const float* hidden = (const float*)d_in[1];
  const float* baw    = (const float*)d_in[2];
  const float* eo     = (const float*)d_in[3];
  const float* emb    = (const float*)d_in[5];
  const float* attn_W = (const float*)d_in[6];
  const float* attn_b = (const float*)d_in[7];
  const float* W_ih0  = (const float*)d_in[8];
  const float* W_hh0  = (const float*)d_in[9];
  const float* b_ih0  = (const float*)d_in[10];
  const float* b_hh0  = (const float*)d_in[11];
  const float* W_ih1  = (const float*)d_in[12];
  const float* W_hh1  = (const float*)d_in[13];
  const float* b_ih1  = (const float*)d_in[14];
  const float* b_hh1  = (const float*)d_in[15];
  const float* out_W  = (const float*)d_in[16];
  const float* out_b  = (const float*)d_in[17];
  float* out = (float*)d_out;

  char* ws = (char*)d_ws;
  float*          q      = (float*)(ws + 0);          //  64*512 f32
  float*          bc     = (float*)(ws + 131072);     //  64*32*512 f32
  float*          ctx    = (float*)(ws + 4325376);    //  64*512 f32
  unsigned short* xcatb  = (unsigned short*)(ws + 4456448);  // 64*1024 bf16
  unsigned short* h0b    = (unsigned short*)(ws + 4587520);  // 64*512
  unsigned short* h1b    = (unsigned short*)(ws + 4653056);  // 64*512
  unsigned short* h0nb   = (unsigned short*)(ws + 4718592);  // 64*512
  unsigned short* outinb = (unsigned short*)(ws + 4784128);  // 64*1024
  float*          gx     = (float*)(ws + 4915200);    // 64*1536 f32
  float*          gh     = (float*)(ws + 5308416);    // 64*1536 f32
  float*          logits = (float*)(ws + 5701632);    // 64*50257 f32

  float* out_lp   = out;
  float* out_nh   = out + 3216448;
  float* out_ctx  = out + 3281984;
  float* out_attw = out + 3314752;

  k_q   <<<dim3(2, 8), 256, 0, stream>>>(hidden, attn_W, q);
  k_attn<<<512, 256, 0, stream>>>(eo, hidden, attn_b, q, bc, out_attw);
  k_prep<<<64, 512, 0, stream>>>(ids, hidden, baw, emb, bc, ctx, xcatb, h0b, h1b, out_ctx);

  k_mv64<1><<<96, 256, 0, stream>>>(W_ih0, b_ih0, xcatb, gx, H3_, 1024, H3_);
  k_mv64<1><<<96, 256, 0, stream>>>(W_hh0, b_hh0, h0b,   gh, H3_, 512,  H3_);
  k_gru<<<64, 512, 0, stream>>>(gx, gh, hidden, out_nh, h0nb,
                                (const float*)nullptr, (unsigned short*)nullptr);

  k_mv64<1><<<96, 256, 0, stream>>>(W_ih1, b_ih1, h0nb, gx, H3_, 512, H3_);
  k_mv64<1><<<96, 256, 0, stream>>>(W_hh1, b_hh1, h1b,  gh, H3_, 512, H3_);
  k_gru<<<64, 512, 0, stream>>>(gx, gh, hidden + B_ * H_, out_nh + B_ * H_, h0nb,
                                ctx, outinb);

  k_mv64<4><<<786, 256, 0, stream>>>(out_W, out_b, outinb, logits, V_, 1024, V_);
  k_lsm<<<64, 1024, 0, stream>>>(logits, out_lp);
}

// Round 2
// 701.313 us; speedup vs baseline: 1.1045x; 1.1045x over previous
//
#include <hip/hip_runtime.h>

#define B_  64
#define S_  2048
#define H_  512
#define V_  50257
#define NB_ 32
#define L_  64
#define H3_ 1536

typedef float  f32x4  __attribute__((ext_vector_type(4)));
typedef __bf16 bf16x8 __attribute__((ext_vector_type(8)));

struct alignas(16) U4 { unsigned int x, y, z, w; };

__device__ __forceinline__ unsigned int f2bf_bits(float f) {
  unsigned int u = __float_as_uint(f);
  return (u + 0x7fffu + ((u >> 16) & 1u)) >> 16;  // RNE
}

__device__ __forceinline__ float wave_sum(float v) {
#pragma unroll
  for (int off = 32; off > 0; off >>= 1) v += __shfl_xor(v, off, 64);
  return v;
}

// q[b,h] = sum_g hidden[1][b,g] * attn_W[g,h]   (64 blocks, 4 b x 128 h each)
__global__ __launch_bounds__(128) void k_q(const float* __restrict__ hidden,
                                           const float* __restrict__ attn_W,
                                           float* __restrict__ q) {
  __shared__ float sh[4 * H_];
  int tid = threadIdx.x;
  int h  = blockIdx.x * 128 + tid;
  int b0 = blockIdx.y * 4;
  const float* h1 = hidden + B_ * H_;
  for (int i = tid; i < 4 * H_; i += 128) sh[i] = h1[b0 * H_ + i];
  __syncthreads();
  float acc[4] = {0.f, 0.f, 0.f, 0.f};
  for (int g = 0; g < H_; ++g) {
    float w = attn_W[(size_t)g * H_ + h];
#pragma unroll
    for (int bb = 0; bb < 4; ++bb) acc[bb] += sh[bb * H_ + g] * w;
  }
#pragma unroll
  for (int bb = 0; bb < 4; ++bb) q[(b0 + bb) * H_ + h] = acc[bb];
}

// One block (4 waves) per (b,n). Wave w handles rows l in [w*16, w*16+16),
// online softmax per wave, softmax-merge across waves in LDS.
__global__ __launch_bounds__(256) void k_attn(
    const float* __restrict__ eo, const float* __restrict__ hidden,
    const float* __restrict__ attn_b, const float* __restrict__ q,
    float* __restrict__ bc, float* __restrict__ attnw_out) {
  __shared__ float sm[4], ss[4];
  __shared__ float shA[4][H_];
  int tid = threadIdx.x;
  int wv = tid >> 6, lane = tid & 63;
  int idx = blockIdx.x;
  int b = idx >> 5, n = idx & 31;

  const float4* qv = (const float4*)(q + (size_t)b * H_);
  float4 q0 = qv[lane], q1 = qv[64 + lane];

  // c0 = dot(hidden[1][b], attn_b)
  const float4* hv = (const float4*)(hidden + (size_t)B_ * H_ + (size_t)b * H_);
  const float4* av = (const float4*)attn_b;
  float4 hx = hv[lane], hy = hv[64 + lane];
  float4 ax = av[lane], ay = av[64 + lane];
  float c0 = hx.x*ax.x + hx.y*ax.y + hx.z*ax.z + hx.w*ax.w
           + hy.x*ay.x + hy.y*ay.y + hy.z*ay.z + hy.w*ay.w;
  c0 = wave_sum(c0);

  const float4* ev = (const float4*)(eo + (size_t)(b * NB_ + n) * L_ * H_);
  float m = -1e30f, s = 0.f, myscore = 0.f;
  float4 A0 = {0,0,0,0}, A1 = {0,0,0,0};
  for (int lr = 0; lr < 16; ++lr) {
    int l = wv * 16 + lr;
    float4 e0 = ev[l * 128 + lane];
    float4 e1 = ev[l * 128 + 64 + lane];
    float p = e0.x*q0.x + e0.y*q0.y + e0.z*q0.z + e0.w*q0.w
            + e1.x*q1.x + e1.y*q1.y + e1.z*q1.z + e1.w*q1.w;
    p = wave_sum(p) + c0;
    if (lane == lr) myscore = p;
    float mnew  = fmaxf(m, p);
    float alpha = __expf(m - mnew);
    float w     = __expf(p - mnew);
    s = s * alpha + w;
    A0.x = A0.x*alpha + w*e0.x; A0.y = A0.y*alpha + w*e0.y;
    A0.z = A0.z*alpha + w*e0.z; A0.w = A0.w*alpha + w*e0.w;
    A1.x = A1.x*alpha + w*e1.x; A1.y = A1.y*alpha + w*e1.y;
    A1.z = A1.z*alpha + w*e1.z; A1.w = A1.w*alpha + w*e1.w;
    m = mnew;
  }
  if (lane == 0) { sm[wv] = m; ss[wv] = s; }
  __syncthreads();
  float m_g = fmaxf(fmaxf(sm[0], sm[1]), fmaxf(sm[2], sm[3]));
  float s_g = ss[0]*__expf(sm[0]-m_g) + ss[1]*__expf(sm[1]-m_g)
            + ss[2]*__expf(sm[2]-m_g) + ss[3]*__expf(sm[3]-m_g);
  float scale = __expf(m - m_g);
  float4* pa = (float4*)&shA[wv][0];
  float4 w0 = {A0.x*scale, A0.y*scale, A0.z*scale, A0.w*scale};
  float4 w1 = {A1.x*scale, A1.y*scale, A1.z*scale, A1.w*scale};
  pa[lane] = w0; pa[64 + lane] = w1;
  __syncthreads();
  float inv = 1.f / s_g;
  float2 sum = {0.f, 0.f};
#pragma unroll
  for (int w = 0; w < 4; ++w) {
    float2 v = ((float2*)&shA[w][0])[tid];
    sum.x += v.x; sum.y += v.y;
  }
  float2* bv = (float2*)(bc + (size_t)(b * NB_ + n) * H_);
  bv[tid] = (float2){sum.x * inv, sum.y * inv};
  if (lane < 16)
    attnw_out[(size_t)(b * NB_ + n) * L_ + wv * 16 + lane] =
        __expf(myscore - m_g) * inv;
}

// context reduce over n, embedding gather, bf16 conversions of x_cat / h0 / h1
__global__ __launch_bounds__(512) void k_prep(
    const int* __restrict__ ids, const float* __restrict__ hidden,
    const float* __restrict__ baw, const float* __restrict__ emb,
    const float* __restrict__ bc, float* __restrict__ ctx,
    unsigned short* __restrict__ xcatb, unsigned short* __restrict__ h0b,
    unsigned short* __restrict__ h1b, float* __restrict__ out_ctx) {
  int b = blockIdx.x, h = threadIdx.x;
  int id = ids[b];
  float ev = emb[(size_t)id * H_ + h];
  float acc = 0.f;
  for (int n = 0; n < NB_; ++n)
    acc += baw[b * NB_ + n] * bc[(size_t)(b * NB_ + n) * H_ + h];
  ctx[b * H_ + h]      = acc;
  out_ctx[b * H_ + h]  = acc;
  xcatb[b * 1024 + h]        = (unsigned short)f2bf_bits(ev);
  xcatb[b * 1024 + 512 + h]  = (unsigned short)f2bf_bits(acc);
  h0b[b * H_ + h] = (unsigned short)f2bf_bits(hidden[b * H_ + h]);
  h1b[b * H_ + h] = (unsigned short)f2bf_bits(hidden[B_ * H_ + b * H_ + h]);
}

// Two fused matvec64 GEMMs (gx and gh): blocks [0,96) do #1, [96,192) do #2.
// Wave covers 16 b-rows x 16 j; 4 waves split b. C = A_bf16 . W^T + bias.
__global__ __launch_bounds__(256) void k_mv2(
    const float* __restrict__ W1, const float* __restrict__ bias1,
    const unsigned short* __restrict__ A1, float* __restrict__ C1, int K1,
    const float* __restrict__ W2, const float* __restrict__ bias2,
    const unsigned short* __restrict__ A2, float* __restrict__ C2, int K2) {
  bool sec = blockIdx.x >= 96;
  const float* W = sec ? W2 : W1;
  const float* bias = sec ? bias2 : bias1;
  const unsigned short* A = sec ? A2 : A1;
  float* C = sec ? C2 : C1;
  int K = sec ? K2 : K1;
  int blk = sec ? blockIdx.x - 96 : blockIdx.x;

  int tid = threadIdx.x;
  int wv = tid >> 6, lane = tid & 63;
  int mrow = lane & 15, qd = lane >> 4;
  int j = blk * 16 + mrow;
  const unsigned short* ap = A + (size_t)(wv * 16 + mrow) * K + qd * 8;
  const float* wp = W + (size_t)j * K + qd * 8;
  f32x4 acc = (f32x4){0.f, 0.f, 0.f, 0.f};
  for (int k0 = 0; k0 < K; k0 += 32) {
    bf16x8 af = __builtin_bit_cast(bf16x8, *(const U4*)(ap + k0));
    float4 w0 = *(const float4*)(wp + k0);
    float4 w1 = *(const float4*)(wp + k0 + 4);
    U4 braw;
    braw.x = f2bf_bits(w0.x) | (f2bf_bits(w0.y) << 16);
    braw.y = f2bf_bits(w0.z) | (f2bf_bits(w0.w) << 16);
    braw.z = f2bf_bits(w1.x) | (f2bf_bits(w1.y) << 16);
    braw.w = f2bf_bits(w1.z) | (f2bf_bits(w1.w) << 16);
    bf16x8 bf = __builtin_bit_cast(bf16x8, braw);
    acc = __builtin_amdgcn_mfma_f32_16x16x32_bf16(af, bf, acc, 0, 0, 0);
  }
  float bv = bias[j];
#pragma unroll
  for (int r = 0; r < 4; ++r) {
    int brow = wv * 16 + qd * 4 + r;
    C[(size_t)brow * H3_ + j] = acc[r] + bv;
  }
}

// Output projection: wave owns 16 j-cols x all 64 b-rows (4 MFMAs / W-frag).
// W loaded + converted once per block. logits[64, V].
__global__ __launch_bounds__(256) void k_out(
    const float* __restrict__ W, const float* __restrict__ bias,
    const unsigned short* __restrict__ A, float* __restrict__ C) {
  int tid = threadIdx.x;
  int wv = tid >> 6, lane = tid & 63;
  int mrow = lane & 15, qd = lane >> 4;
  int j = blockIdx.x * 64 + wv * 16 + mrow;
  int jc = j < V_ ? j : V_ - 1;
  const float* wp = W + (size_t)jc * 1024 + qd * 8;
  const unsigned short* ap = A + mrow * 1024 + qd * 8;
  f32x4 acc[4];
#pragma unroll
  for (int r = 0; r < 4; ++r) acc[r] = (f32x4){0.f, 0.f, 0.f, 0.f};
  for (int k0 = 0; k0 < 1024; k0 += 32) {
    float4 w0 = *(const float4*)(wp + k0);
    float4 w1 = *(const float4*)(wp + k0 + 4);
    U4 braw;
    braw.x = f2bf_bits(w0.x) | (f2bf_bits(w0.y) << 16);
    braw.y = f2bf_bits(w0.z) | (f2bf_bits(w0.w) << 16);
    braw.z = f2bf_bits(w1.x) | (f2bf_bits(w1.y) << 16);
    braw.w = f2bf_bits(w1.z) | (f2bf_bits(w1.w) << 16);
    bf16x8 bw = __builtin_bit_cast(bf16x8, braw);
#pragma unroll
    for (int r = 0; r < 4; ++r) {
      bf16x8 af = __builtin_bit_cast(bf16x8, *(const U4*)(ap + r * 16 * 1024 + k0));
      acc[r] = __builtin_amdgcn_mfma_f32_16x16x32_bf16(af, bw, acc[r], 0, 0, 0);
    }
  }
  if (j < V_) {
    float bv = bias[j];
#pragma unroll
    for (int r = 0; r < 4; ++r) {
#pragma unroll
      for (int g = 0; g < 4; ++g) {
        int brow = r * 16 + qd * 4 + g;
        C[(size_t)brow * V_ + j] = acc[r][g] + bv;
      }
    }
  }
}

// GRU gate combine. Optionally builds out_in bf16 = [h_new | context].
__global__ __launch_bounds__(512) void k_gru(
    const float* __restrict__ gx, const float* __restrict__ gh,
    const float* __restrict__ hprev, float* __restrict__ hnew_out,
    unsigned short* __restrict__ hnew_bf, const float* __restrict__ ctx,
    unsigned short* __restrict__ outin) {
  int b = blockIdx.x, i = threadIdx.x;
  size_t g0 = (size_t)b * H3_ + i;
  float xr = gx[g0], xz = gx[g0 + 512], xn = gx[g0 + 1024];
  float hr = gh[g0], hz = gh[g0 + 512], hn = gh[g0 + 1024];
  float r  = 1.f / (1.f + __expf(-(xr + hr)));
  float z  = 1.f / (1.f + __expf(-(xz + hz)));
  float nn = tanhf(xn + r * hn);
  float hp = hprev[b * H_ + i];
  float h  = (1.f - z) * nn + z * hp;
  hnew_out[b * H_ + i] = h;
  hnew_bf[b * H_ + i]  = (unsigned short)f2bf_bits(h);
  if (outin) {
    outin[b * 1024 + i]       = (unsigned short)f2bf_bits(h);
    outin[b * 1024 + 512 + i] = (unsigned short)f2bf_bits(ctx[b * H_ + i]);
  }
}

__global__ __launch_bounds__(1024) void k_lsm(const float* __restrict__ logits,
                                              float* __restrict__ out) {
  int b = blockIdx.x, tid = threadIdx.x;
  int lane = tid & 63, wid = tid >> 6;
  const float* row = logits + (size_t)b * V_;
  __shared__ float red[16];
  float mx = -1e30f;
  for (int j = tid; j < V_; j += 1024) mx = fmaxf(mx, row[j]);
#pragma unroll
  for (int off = 32; off > 0; off >>= 1) mx = fmaxf(mx, __shfl_xor(mx, off, 64));
  if (lane == 0) red[wid] = mx;
  __syncthreads();
  if (tid == 0) {
    float v = red[0];
    for (int i = 1; i < 16; ++i) v = fmaxf(v, red[i]);
    red[0] = v;
  }
  __syncthreads();
  mx = red[0];
  __syncthreads();
  float s = 0.f;
  for (int j = tid; j < V_; j += 1024) s += __expf(row[j] - mx);
  s = wave_sum(s);
  if (lane == 0) red[wid] = s;
  __syncthreads();
  if (tid == 0) {
    float v = 0.f;
    for (int i = 0; i < 16; ++i) v += red[i];
    red[0] = logf(v);
  }
  __syncthreads();
  float lse = mx + red[0];
  for (int j = tid; j < V_; j += 1024) out[(size_t)b * V_ + j] = row[j] - lse;
}

extern "C" void kernel_launch(void* const* d_in, const int* in_sizes, int n_in,
                              void* d_out, int out_size, void* d_ws, size_t ws_size,
                              hipStream_t stream) {
  const int*   ids    = (const int*)d_in[0];
  const float* hidden = (const float*)d_in[1];
  const float* baw    = (const float*)d_in[2];
  const float* eo     = (const float*)d_in[3];
  const float* emb    = (const float*)d_in[5];
  const float* attn_W = (const float*)d_in[6];
  const float* attn_b = (const float*)d_in[7];
  const float* W_ih0  = (const float*)d_in[8];
  const float* W_hh0  = (const float*)d_in[9];
  const float* b_ih0  = (const float*)d_in[10];
  const float* b_hh0  = (const float*)d_in[11];
  const float* W_ih1  = (const float*)d_in[12];
  const float* W_hh1  = (const float*)d_in[13];
  const float* b_ih1  = (const float*)d_in[14];
  const float* b_hh1  = (const float*)d_in[15];
  const float* out_W  = (const float*)d_in[16];
  const float* out_b  = (const float*)d_in[17];
  float* out = (float*)d_out;

  char* ws = (char*)d_ws;
  float*          q      = (float*)(ws + 0);          //  64*512 f32
  float*          bc     = (float*)(ws + 131072);     //  64*32*512 f32
  float*          ctx    = (float*)(ws + 4325376);    //  64*512 f32
  unsigned short* xcatb  = (unsigned short*)(ws + 4456448);  // 64*1024 bf16
  unsigned short* h0b    = (unsigned short*)(ws + 4587520);  // 64*512
  unsigned short* h1b    = (unsigned short*)(ws + 4653056);  // 64*512
  unsigned short* h0nb   = (unsigned short*)(ws + 4718592);  // 64*512
  unsigned short* outinb = (unsigned short*)(ws + 4784128);  // 64*1024
  float*          gx     = (float*)(ws + 4915200);    // 64*1536 f32
  float*          gh     = (float*)(ws + 5308416);    // 64*1536 f32
  float*          logits = (float*)(ws + 5701632);    // 64*50257 f32

  float* out_lp   = out;
  float* out_nh   = out + 3216448;
  float* out_ctx  = out + 3281984;
  float* out_attw = out + 3314752;

  k_q   <<<dim3(4, 16), 128, 0, stream>>>(hidden, attn_W, q);
  k_attn<<<2048, 256, 0, stream>>>(eo, hidden, attn_b, q, bc, out_attw);
  k_prep<<<64, 512, 0, stream>>>(ids, hidden, baw, emb, bc, ctx, xcatb, h0b, h1b, out_ctx);

  k_mv2<<<192, 256, 0, stream>>>(W_ih0, b_ih0, xcatb, gx, 1024,
                                 W_hh0, b_hh0, h0b,   gh, 512);
  k_gru<<<64, 512, 0, stream>>>(gx, gh, hidden, out_nh, h0nb,
                                (const float*)nullptr, (unsigned short*)nullptr);

  k_mv2<<<192, 256, 0, stream>>>(W_ih1, b_ih1, h0nb, gx, 512,
                                 W_hh1, b_hh1, h1b,  gh, 512);
  k_gru<<<64, 512, 0, stream>>>(gx, gh, hidden + B_ * H_, out_nh + B_ * H_, h0nb,
                                ctx, outinb);

  k_out<<<786, 256, 0, stream>>>(out_W, out_b, outinb, logits);
  k_lsm<<<64, 1024, 0, stream>>>(logits, out_lp);
}

// Round 3
// 691.178 us; speedup vs baseline: 1.1207x; 1.0147x over previous
//
#include <hip/hip_runtime.h>

#define B_  64
#define S_  2048
#define H_  512
#define V_  50257
#define NB_ 32
#define L_  64
#define H3_ 1536

typedef float  f32x4  __attribute__((ext_vector_type(4)));
typedef __bf16 bf16x8 __attribute__((ext_vector_type(8)));

struct alignas(16) U4 { unsigned int x, y, z, w; };

__device__ __forceinline__ unsigned int f2bf_bits(float f) {
  unsigned int u = __float_as_uint(f);
  return (u + 0x7fffu + ((u >> 16) & 1u)) >> 16;  // RNE
}

__device__ __forceinline__ f32x4 ntload4(const float* p) {
  return __builtin_nontemporal_load((const f32x4*)p);
}

__device__ __forceinline__ float wave_sum(float v) {
#pragma unroll
  for (int off = 32; off > 0; off >>= 1) v += __shfl_xor(v, off, 64);
  return v;
}

// q[b,h] = sum_g hidden[1][b,g] * attn_W[g,h]   (64 blocks, 4 b x 128 h each)
__global__ __launch_bounds__(128) void k_q(const float* __restrict__ hidden,
                                           const float* __restrict__ attn_W,
                                           float* __restrict__ q) {
  __shared__ float sh[4 * H_];
  int tid = threadIdx.x;
  int h  = blockIdx.x * 128 + tid;
  int b0 = blockIdx.y * 4;
  const float* h1 = hidden + B_ * H_;
  for (int i = tid; i < 4 * H_; i += 128) sh[i] = h1[b0 * H_ + i];
  __syncthreads();
  float acc[4] = {0.f, 0.f, 0.f, 0.f};
  for (int g = 0; g < H_; ++g) {
    float w = attn_W[(size_t)g * H_ + h];
#pragma unroll
    for (int bb = 0; bb < 4; ++bb) acc[bb] += sh[bb * H_ + g] * w;
  }
#pragma unroll
  for (int bb = 0; bb < 4; ++bb) q[(b0 + bb) * H_ + h] = acc[bb];
}

// One block (4 waves) per (b,n). Wave w handles rows [w*16, w*16+16), 2 rows
// per iteration (halved serial softmax chain); merge across waves in LDS.
__global__ __launch_bounds__(256) void k_attn(
    const float* __restrict__ eo, const float* __restrict__ hidden,
    const float* __restrict__ attn_b, const float* __restrict__ q,
    float* __restrict__ bc, float* __restrict__ attnw_out) {
  __shared__ float sm[4], ss[4];
  __shared__ float shA[4][H_];
  int tid = threadIdx.x;
  int wv = tid >> 6, lane = tid & 63;
  int idx = blockIdx.x;
  int b = idx >> 5, n = idx & 31;

  f32x4 q0 = *(const f32x4*)(q + (size_t)b * H_ + lane * 4);
  f32x4 q1 = *(const f32x4*)(q + (size_t)b * H_ + 256 + lane * 4);

  // c0 = dot(hidden[1][b], attn_b)
  const float* hp = hidden + (size_t)B_ * H_ + (size_t)b * H_;
  f32x4 hx = *(const f32x4*)(hp + lane * 4);
  f32x4 hy = *(const f32x4*)(hp + 256 + lane * 4);
  f32x4 ax = *(const f32x4*)(attn_b + lane * 4);
  f32x4 ay = *(const f32x4*)(attn_b + 256 + lane * 4);
  float c0 = hx.x*ax.x + hx.y*ax.y + hx.z*ax.z + hx.w*ax.w
           + hy.x*ay.x + hy.y*ay.y + hy.z*ay.z + hy.w*ay.w;
  c0 = wave_sum(c0);

  const float* eb = eo + (size_t)(b * NB_ + n) * L_ * H_;
  float m = -1e30f, s = 0.f, myscore = 0.f;
  f32x4 A0 = {0,0,0,0}, A1 = {0,0,0,0};
  for (int lr = 0; lr < 16; lr += 2) {
    const float* rA = eb + (size_t)(wv * 16 + lr) * H_;
    const float* rB = rA + H_;
    f32x4 a0 = ntload4(rA + lane * 4);
    f32x4 a1 = ntload4(rA + 256 + lane * 4);
    f32x4 b0 = ntload4(rB + lane * 4);
    f32x4 b1 = ntload4(rB + 256 + lane * 4);
    float pa = a0.x*q0.x + a0.y*q0.y + a0.z*q0.z + a0.w*q0.w
             + a1.x*q1.x + a1.y*q1.y + a1.z*q1.z + a1.w*q1.w;
    float pb = b0.x*q0.x + b0.y*q0.y + b0.z*q0.z + b0.w*q0.w
             + b1.x*q1.x + b1.y*q1.y + b1.z*q1.z + b1.w*q1.w;
#pragma unroll
    for (int off = 32; off > 0; off >>= 1) {
      pa += __shfl_xor(pa, off, 64);
      pb += __shfl_xor(pb, off, 64);
    }
    pa += c0; pb += c0;
    if (lane == lr)     myscore = pa;
    if (lane == lr + 1) myscore = pb;
    float mnew  = fmaxf(m, fmaxf(pa, pb));
    float alpha = __expf(m - mnew);
    float wa    = __expf(pa - mnew);
    float wb    = __expf(pb - mnew);
    s = s * alpha + wa + wb;
    A0.x = A0.x*alpha + wa*a0.x + wb*b0.x;
    A0.y = A0.y*alpha + wa*a0.y + wb*b0.y;
    A0.z = A0.z*alpha + wa*a0.z + wb*b0.z;
    A0.w = A0.w*alpha + wa*a0.w + wb*b0.w;
    A1.x = A1.x*alpha + wa*a1.x + wb*b1.x;
    A1.y = A1.y*alpha + wa*a1.y + wb*b1.y;
    A1.z = A1.z*alpha + wa*a1.z + wb*b1.z;
    A1.w = A1.w*alpha + wa*a1.w + wb*b1.w;
    m = mnew;
  }
  if (lane == 0) { sm[wv] = m; ss[wv] = s; }
  __syncthreads();
  float m_g = fmaxf(fmaxf(sm[0], sm[1]), fmaxf(sm[2], sm[3]));
  float s_g = ss[0]*__expf(sm[0]-m_g) + ss[1]*__expf(sm[1]-m_g)
            + ss[2]*__expf(sm[2]-m_g) + ss[3]*__expf(sm[3]-m_g);
  float scale = __expf(m - m_g);
  f32x4* pa4 = (f32x4*)&shA[wv][0];
  f32x4 w0 = {A0.x*scale, A0.y*scale, A0.z*scale, A0.w*scale};
  f32x4 w1 = {A1.x*scale, A1.y*scale, A1.z*scale, A1.w*scale};
  pa4[lane] = w0; pa4[64 + lane] = w1;
  __syncthreads();
  float inv = 1.f / s_g;
  float2 sum = {0.f, 0.f};
#pragma unroll
  for (int w = 0; w < 4; ++w) {
    float2 v = ((float2*)&shA[w][0])[tid];
    sum.x += v.x; sum.y += v.y;
  }
  float2* bv = (float2*)(bc + (size_t)(b * NB_ + n) * H_);
  bv[tid] = (float2){sum.x * inv, sum.y * inv};
  if (lane < 16)
    attnw_out[(size_t)(b * NB_ + n) * L_ + wv * 16 + lane] =
        __expf(myscore - m_g) * inv;
}

// context reduce over n, embedding gather, bf16 conversions of x_cat / h0 / h1
__global__ __launch_bounds__(512) void k_prep(
    const int* __restrict__ ids, const float* __restrict__ hidden,
    const float* __restrict__ baw, const float* __restrict__ emb,
    const float* __restrict__ bc, float* __restrict__ ctx,
    unsigned short* __restrict__ xcatb, unsigned short* __restrict__ h0b,
    unsigned short* __restrict__ h1b, float* __restrict__ out_ctx) {
  int b = blockIdx.x, h = threadIdx.x;
  int id = ids[b];
  float ev = emb[(size_t)id * H_ + h];
  float acc = 0.f;
  for (int n = 0; n < NB_; ++n)
    acc += baw[b * NB_ + n] * bc[(size_t)(b * NB_ + n) * H_ + h];
  ctx[b * H_ + h]      = acc;
  out_ctx[b * H_ + h]  = acc;
  xcatb[b * 1024 + h]        = (unsigned short)f2bf_bits(ev);
  xcatb[b * 1024 + 512 + h]  = (unsigned short)f2bf_bits(acc);
  h0b[b * H_ + h] = (unsigned short)f2bf_bits(hidden[b * H_ + h]);
  h1b[b * H_ + h] = (unsigned short)f2bf_bits(hidden[B_ * H_ + b * H_ + h]);
}

// Two fused matvec64 GEMMs (gx and gh): blocks [0,96) do #1, [96,192) do #2.
__global__ __launch_bounds__(256) void k_mv2(
    const float* __restrict__ W1, const float* __restrict__ bias1,
    const unsigned short* __restrict__ A1, float* __restrict__ C1, int K1,
    const float* __restrict__ W2, const float* __restrict__ bias2,
    const unsigned short* __restrict__ A2, float* __restrict__ C2, int K2) {
  bool sec = blockIdx.x >= 96;
  const float* W = sec ? W2 : W1;
  const float* bias = sec ? bias2 : bias1;
  const unsigned short* A = sec ? A2 : A1;
  float* C = sec ? C2 : C1;
  int K = sec ? K2 : K1;
  int blk = sec ? blockIdx.x - 96 : blockIdx.x;

  int tid = threadIdx.x;
  int wv = tid >> 6, lane = tid & 63;
  int mrow = lane & 15, qd = lane >> 4;
  int j = blk * 16 + mrow;
  const unsigned short* ap = A + (size_t)(wv * 16 + mrow) * K + qd * 8;
  const float* wp = W + (size_t)j * K + qd * 8;
  f32x4 acc = (f32x4){0.f, 0.f, 0.f, 0.f};
  for (int k0 = 0; k0 < K; k0 += 32) {
    bf16x8 af = __builtin_bit_cast(bf16x8, *(const U4*)(ap + k0));
    f32x4 w0 = *(const f32x4*)(wp + k0);
    f32x4 w1 = *(const f32x4*)(wp + k0 + 4);
    U4 braw;
    braw.x = f2bf_bits(w0.x) | (f2bf_bits(w0.y) << 16);
    braw.y = f2bf_bits(w0.z) | (f2bf_bits(w0.w) << 16);
    braw.z = f2bf_bits(w1.x) | (f2bf_bits(w1.y) << 16);
    braw.w = f2bf_bits(w1.z) | (f2bf_bits(w1.w) << 16);
    bf16x8 bf = __builtin_bit_cast(bf16x8, braw);
    acc = __builtin_amdgcn_mfma_f32_16x16x32_bf16(af, bf, acc, 0, 0, 0);
  }
  float bv = bias[j];
#pragma unroll
  for (int r = 0; r < 4; ++r) {
    int brow = wv * 16 + qd * 4 + r;
    C[(size_t)brow * H3_ + j] = acc[r] + bv;
  }
}

// Output projection: wave owns 16 j-cols x all 64 b-rows (4 MFMAs / W-frag).
// W streamed nontemporal (read-once), converted to bf16 once per block.
__global__ __launch_bounds__(256) void k_out(
    const float* __restrict__ W, const float* __restrict__ bias,
    const unsigned short* __restrict__ A, float* __restrict__ C) {
  int tid = threadIdx.x;
  int wv = tid >> 6, lane = tid & 63;
  int mrow = lane & 15, qd = lane >> 4;
  int j = blockIdx.x * 64 + wv * 16 + mrow;
  int jc = j < V_ ? j : V_ - 1;
  const float* wp = W + (size_t)jc * 1024 + qd * 8;
  const unsigned short* ap = A + mrow * 1024 + qd * 8;
  f32x4 acc[4];
#pragma unroll
  for (int r = 0; r < 4; ++r) acc[r] = (f32x4){0.f, 0.f, 0.f, 0.f};
  for (int k0 = 0; k0 < 1024; k0 += 32) {
    f32x4 w0 = ntload4(wp + k0);
    f32x4 w1 = ntload4(wp + k0 + 4);
    U4 braw;
    braw.x = f2bf_bits(w0.x) | (f2bf_bits(w0.y) << 16);
    braw.y = f2bf_bits(w0.z) | (f2bf_bits(w0.w) << 16);
    braw.z = f2bf_bits(w1.x) | (f2bf_bits(w1.y) << 16);
    braw.w = f2bf_bits(w1.z) | (f2bf_bits(w1.w) << 16);
    bf16x8 bw = __builtin_bit_cast(bf16x8, braw);
#pragma unroll
    for (int r = 0; r < 4; ++r) {
      bf16x8 af = __builtin_bit_cast(bf16x8, *(const U4*)(ap + r * 16 * 1024 + k0));
      acc[r] = __builtin_amdgcn_mfma_f32_16x16x32_bf16(af, bw, acc[r], 0, 0, 0);
    }
  }
  if (j < V_) {
    float bv = bias[j];
#pragma unroll
    for (int r = 0; r < 4; ++r) {
#pragma unroll
      for (int g = 0; g < 4; ++g) {
        int brow = r * 16 + qd * 4 + g;
        C[(size_t)brow * V_ + j] = acc[r][g] + bv;
      }
    }
  }
}

// GRU gate combine. Optionally builds out_in bf16 = [h_new | context].
__global__ __launch_bounds__(512) void k_gru(
    const float* __restrict__ gx, const float* __restrict__ gh,
    const float* __restrict__ hprev, float* __restrict__ hnew_out,
    unsigned short* __restrict__ hnew_bf, const float* __restrict__ ctx,
    unsigned short* __restrict__ outin) {
  int b = blockIdx.x, i = threadIdx.x;
  size_t g0 = (size_t)b * H3_ + i;
  float xr = gx[g0], xz = gx[g0 + 512], xn = gx[g0 + 1024];
  float hr = gh[g0], hz = gh[g0 + 512], hn = gh[g0 + 1024];
  float r  = 1.f / (1.f + __expf(-(xr + hr)));
  float z  = 1.f / (1.f + __expf(-(xz + hz)));
  float nn = tanhf(xn + r * hn);
  float hp = hprev[b * H_ + i];
  float h  = (1.f - z) * nn + z * hp;
  hnew_out[b * H_ + i] = h;
  hnew_bf[b * H_ + i]  = (unsigned short)f2bf_bits(h);
  if (outin) {
    outin[b * 1024 + i]       = (unsigned short)f2bf_bits(h);
    outin[b * 1024 + 512 + i] = (unsigned short)f2bf_bits(ctx[b * H_ + i]);
  }
}

// log_softmax: single online max/sum-exp pass + write pass.
__global__ __launch_bounds__(1024) void k_lsm(const float* __restrict__ logits,
                                              float* __restrict__ out) {
  int b = blockIdx.x, tid = threadIdx.x;
  int lane = tid & 63, wid = tid >> 6;
  const float* row = logits + (size_t)b * V_;
  __shared__ float redm[16], reds[16], bl[1];
  float m_t = -1e30f, s_t = 0.f;
  for (int j = tid; j < V_; j += 1024) {
    float x = row[j];
    if (x > m_t) {              // rare: rescale
      s_t = s_t * __expf(m_t - x) + 1.f;
      m_t = x;
    } else {
      s_t += __expf(x - m_t);
    }
  }
#pragma unroll
  for (int off = 32; off > 0; off >>= 1) {
    float mo = __shfl_xor(m_t, off, 64);
    float so = __shfl_xor(s_t, off, 64);
    float mn = fmaxf(m_t, mo);
    s_t = s_t * __expf(m_t - mn) + so * __expf(mo - mn);
    m_t = mn;
  }
  if (lane == 0) { redm[wid] = m_t; reds[wid] = s_t; }
  __syncthreads();
  if (tid == 0) {
    float m_g = redm[0], s_g = reds[0];
    for (int i = 1; i < 16; ++i) {
      float mn = fmaxf(m_g, redm[i]);
      s_g = s_g * __expf(m_g - mn) + reds[i] * __expf(redm[i] - mn);
      m_g = mn;
    }
    bl[0] = m_g + logf(s_g);
  }
  __syncthreads();
  float lse = bl[0];
  float* orow = out + (size_t)b * V_;
  for (int j = tid; j < V_; j += 1024)
    __builtin_nontemporal_store(row[j] - lse, orow + j);
}

extern "C" void kernel_launch(void* const* d_in, const int* in_sizes, int n_in,
                              void* d_out, int out_size, void* d_ws, size_t ws_size,
                              hipStream_t stream) {
  const int*   ids    = (const int*)d_in[0];
  const float* hidden = (const float*)d_in[1];
  const float* baw    = (const float*)d_in[2];
  const float* eo     = (const float*)d_in[3];
  const float* emb    = (const float*)d_in[5];
  const float* attn_W = (const float*)d_in[6];
  const float* attn_b = (const float*)d_in[7];
  const float* W_ih0  = (const float*)d_in[8];
  const float* W_hh0  = (const float*)d_in[9];
  const float* b_ih0  = (const float*)d_in[10];
  const float* b_hh0  = (const float*)d_in[11];
  const float* W_ih1  = (const float*)d_in[12];
  const float* W_hh1  = (const float*)d_in[13];
  const float* b_ih1  = (const float*)d_in[14];
  const float* b_hh1  = (const float*)d_in[15];
  const float* out_W  = (const float*)d_in[16];
  const float* out_b  = (const float*)d_in[17];
  float* out = (float*)d_out;

  char* ws = (char*)d_ws;
  float*          q      = (float*)(ws + 0);          //  64*512 f32
  float*          bc     = (float*)(ws + 131072);     //  64*32*512 f32
  float*          ctx    = (float*)(ws + 4325376);    //  64*512 f32
  unsigned short* xcatb  = (unsigned short*)(ws + 4456448);  // 64*1024 bf16
  unsigned short* h0b    = (unsigned short*)(ws + 4587520);  // 64*512
  unsigned short* h1b    = (unsigned short*)(ws + 4653056);  // 64*512
  unsigned short* h0nb   = (unsigned short*)(ws + 4718592);  // 64*512
  unsigned short* outinb = (unsigned short*)(ws + 4784128);  // 64*1024
  float*          gx     = (float*)(ws + 4915200);    // 64*1536 f32
  float*          gh     = (float*)(ws + 5308416);    // 64*1536 f32
  float*          logits = (float*)(ws + 5701632);    // 64*50257 f32

  float* out_lp   = out;
  float* out_nh   = out + 3216448;
  float* out_ctx  = out + 3281984;
  float* out_attw = out + 3314752;

  k_q   <<<dim3(4, 16), 128, 0, stream>>>(hidden, attn_W, q);
  k_attn<<<2048, 256, 0, stream>>>(eo, hidden, attn_b, q, bc, out_attw);
  k_prep<<<64, 512, 0, stream>>>(ids, hidden, baw, emb, bc, ctx, xcatb, h0b, h1b, out_ctx);

  k_mv2<<<192, 256, 0, stream>>>(W_ih0, b_ih0, xcatb, gx, 1024,
                                 W_hh0, b_hh0, h0b,   gh, 512);
  k_gru<<<64, 512, 0, stream>>>(gx, gh, hidden, out_nh, h0nb,
                                (const float*)nullptr, (unsigned short*)nullptr);

  k_mv2<<<192, 256, 0, stream>>>(W_ih1, b_ih1, h0nb, gx, 512,
                                 W_hh1, b_hh1, h1b,  gh, 512);
  k_gru<<<64, 512, 0, stream>>>(gx, gh, hidden + B_ * H_, out_nh + B_ * H_, h0nb,
                                ctx, outinb);

  k_out<<<786, 256, 0, stream>>>(out_W, out_b, outinb, logits);
  k_lsm<<<64, 1024, 0, stream>>>(logits, out_lp);
}